// Round 4
// baseline (122.274 us; speedup 1.0000x reference)
//
#include <hip/hip_runtime.h>
#include <hip/hip_bf16.h>

// Fused GAT layer, bf16-MFMA, round 4: software-pipelined multi-tile blocks.
// Grid 1024 = 8 b x 128 groups; each block does 4 tiles (2 n-rows each, 8 n total).
// Per tile: stage x^T (bf16, LDS [64][140hw], dbuf) -> 32 MFMA -> softmax epilogue.
// Pipeline: loads for tile t+2 issued before epilogue(t); cvt+ds_write(t+1) right
// after MFMA(t); ONE barrier per tile. B-frags (W^T bf16 via prep kernel) loaded once.

#define NK 32768
#define NEG_SLOPE 0.2f
#define TILES 4

using f32x4 = __attribute__((ext_vector_type(4))) float;
using s16x8 = __attribute__((ext_vector_type(8))) short;

__device__ __forceinline__ unsigned short f2bf(float f) {   // RNE float->bf16
    unsigned u = __float_as_uint(f);
    return (unsigned short)((u + 0x7FFFu + ((u >> 16) & 1u)) >> 16);
}

// Wt[g][f] = bf16(W[f][g])
__global__ __launch_bounds__(256) void prep_wt(
    const float* __restrict__ W, unsigned short* __restrict__ Wt)
{
    const int i = blockIdx.x * 256 + threadIdx.x;
    Wt[i] = f2bf(W[(i & 127) * 128 + (i >> 7)]);
}

__global__ __launch_bounds__(256) void fused_gat_mfma(
    const float* __restrict__ x,
    const int*   __restrict__ core_types,
    const int*   __restrict__ target_types,
    const unsigned short* __restrict__ Wt,
    const float* __restrict__ a_pair,
    float* __restrict__ out,
    float* __restrict__ att_out)
{
    // packed bf16x2 x^T tile: [buf][m(64)][fp(64 of 70)] ; row stride 70 words
    // write bank: 4-way (free-ish); b128 read: conflict-free (70w stride -> 6*l15 mod 32)
    __shared__ unsigned xs[2][64 * 70];

    const int t    = threadIdx.x;
    const int wv   = __builtin_amdgcn_readfirstlane(t >> 6);
    const int lane = t & 63, l15 = lane & 15, l4 = lane >> 4;
    const int b    = blockIdx.x >> 7;
    const int nb   = (blockIdx.x & 127) * 8;          // 8 n-rows per block

    const int m2  = (t & 31) * 2;                     // staging: m pair base
    const int fpg = t >> 5;                           // staging: f-pair group 0..7

    // ---- B fragments once per block (L2-hot bf16 W^T)
    s16x8 bfrag[2][4];
    #pragma unroll
    for (int gt = 0; gt < 2; ++gt) {
        const unsigned short* wr = Wt + (wv * 32 + gt * 16 + l15) * 128 + l4 * 8;
        #pragma unroll
        for (int fs = 0; fs < 4; ++fs) bfrag[gt][fs] = *(const s16x8*)(wr + fs * 32);
    }

    const float* xb0 = x + (size_t)b * 128 * NK + (size_t)nb * 32;

    float2 plo[8], phi[8];                            // prefetch regs (32 VGPR transient)

    auto ISSUE = [&](int tt) {
        const float* xb = xb0 + tt * 64;
        #pragma unroll
        for (int r = 0; r < 8; ++r) {
            const int fp = fpg + r * 8;
            plo[r] = *(const float2*)&xb[(size_t)(2 * fp)     * NK + m2];
            phi[r] = *(const float2*)&xb[(size_t)(2 * fp + 1) * NK + m2];
        }
    };
    auto CVTW = [&](int buf) {
        unsigned* d = xs[buf];
        #pragma unroll
        for (int r = 0; r < 8; ++r) {
            const int fp = fpg + r * 8;
            __hip_bfloat162 h0 = __float22bfloat162_rn(make_float2(plo[r].x, phi[r].x));
            __hip_bfloat162 h1 = __float22bfloat162_rn(make_float2(plo[r].y, phi[r].y));
            d[m2 * 70 + fp]       = *(unsigned*)&h0;   // v_cvt_pk_bf16_f32 path
            d[(m2 + 1) * 70 + fp] = *(unsigned*)&h1;
        }
    };

    // ---- prologue
    ISSUE(0);
    CVTW(0);
    ISSUE(1);

    for (int tt = 0; tt < TILES; ++tt) {
        __syncthreads();                               // buf[tt&1] ready for all waves
        const unsigned short* xsu = (const unsigned short*)xs[tt & 1];
        const int n0 = nb + 2 * tt;

        // ---- MFMA (both n-rows) : acc[nl][h][gt], m = nl*32+16h+l4*4+r, g = 32wv+16gt+l15
        f32x4 acc[2][2][2];
        #pragma unroll
        for (int nl = 0; nl < 2; ++nl)
            #pragma unroll
            for (int h = 0; h < 2; ++h)
                #pragma unroll
                for (int gt = 0; gt < 2; ++gt) acc[nl][h][gt] = (f32x4){0.f, 0.f, 0.f, 0.f};

        #pragma unroll
        for (int fs = 0; fs < 4; ++fs) {
            #pragma unroll
            for (int nl = 0; nl < 2; ++nl) {
                s16x8 a0 = *(const s16x8*)&xsu[(nl * 32 +      l15) * 140 + fs * 32 + l4 * 8];
                s16x8 a1 = *(const s16x8*)&xsu[(nl * 32 + 16 + l15) * 140 + fs * 32 + l4 * 8];
                #pragma unroll
                for (int gt = 0; gt < 2; ++gt) {
                    acc[nl][0][gt] = __builtin_amdgcn_mfma_f32_16x16x32_bf16(a0, bfrag[gt][fs], acc[nl][0][gt], 0, 0, 0);
                    acc[nl][1][gt] = __builtin_amdgcn_mfma_f32_16x16x32_bf16(a1, bfrag[gt][fs], acc[nl][1][gt], 0, 0, 0);
                }
            }
        }

        // ---- stage next tile into other buffer; issue loads for tile tt+2
        if (tt + 1 < TILES) CVTW((tt + 1) & 1);
        if (tt + 2 < TILES) ISSUE(tt + 2);

        // ---- epilogue per n-row
        #pragma unroll
        for (int nl = 0; nl < 2; ++nl) {
            const int n  = n0 + nl;
            const int cc = core_types[b * 1024 + n];   // block-uniform -> s_load

            float ev[2][2][4];
            #pragma unroll
            for (int h = 0; h < 2; ++h) {
                const int kb = 16 * h + l4 * 4;
                const int4 tt4 = *(const int4*)&target_types[((size_t)(b * 1024 + n)) * 32 + kb];
                const int ttv[4] = {tt4.x, tt4.y, tt4.z, tt4.w};
                #pragma unroll
                for (int r = 0; r < 4; ++r) {
                    const int tv = ttv[r];
                    const int lo = min(cc, tv), hi = max(cc, tv);
                    const int idx = lo * (17 - lo) / 2 + (hi - lo);
                    const float* arow = a_pair + idx * 128 + wv * 32 + l15;
                    #pragma unroll
                    for (int gt = 0; gt < 2; ++gt) {
                        const float e = acc[nl][h][gt][r] * arow[gt * 16];
                        ev[h][gt][r] = e > 0.f ? e : NEG_SLOPE * e;
                    }
                }
            }

            // softmax over k (8 regs x 4-lane group: xor 16, 32)
            #pragma unroll
            for (int gt = 0; gt < 2; ++gt) {
                float mx = -1e30f;
                #pragma unroll
                for (int h = 0; h < 2; ++h)
                    #pragma unroll
                    for (int r = 0; r < 4; ++r) mx = fmaxf(mx, ev[h][gt][r]);
                mx = fmaxf(mx, __shfl_xor(mx, 16));
                mx = fmaxf(mx, __shfl_xor(mx, 32));
                float sm = 0.f;
                #pragma unroll
                for (int h = 0; h < 2; ++h)
                    #pragma unroll
                    for (int r = 0; r < 4; ++r) {
                        const float p = __expf(ev[h][gt][r] - mx);
                        ev[h][gt][r] = p;
                        sm += p;
                    }
                sm += __shfl_xor(sm, 16);
                sm += __shfl_xor(sm, 32);
                const float inv = __fdividef(1.f, sm);
                #pragma unroll
                for (int h = 0; h < 2; ++h)
                    #pragma unroll
                    for (int r = 0; r < 4; ++r) ev[h][gt][r] *= inv;
            }

            // stores
            #pragma unroll
            for (int h = 0; h < 2; ++h) {
                const int kb = 16 * h + l4 * 4;
                #pragma unroll
                for (int gt = 0; gt < 2; ++gt) {
                    const int g = wv * 32 + gt * 16 + l15;
                    f32x4 ov;
                    #pragma unroll
                    for (int r = 0; r < 4; ++r) {
                        const float hh = ev[h][gt][r] * acc[nl][h][gt][r];
                        ov[r] = hh > 0.f ? hh : __expf(hh) - 1.f;
                    }
                    *(f32x4*)&out[(size_t)b * 128 * NK + (size_t)g * NK + n * 32 + kb] = ov;
                }
                #pragma unroll
                for (int r = 0; r < 4; ++r) {
                    const size_t abase = (((size_t)(b * 1024 + n)) * 32 + kb + r) * 128 + wv * 32 + l15;
                    att_out[abase]      = ev[h][0][r];
                    att_out[abase + 16] = ev[h][1][r];
                }
            }
        }
    }
}

extern "C" void kernel_launch(void* const* d_in, const int* in_sizes, int n_in,
                              void* d_out, int out_size, void* d_ws, size_t ws_size,
                              hipStream_t stream) {
    const float* x    = (const float*)d_in[0];
    const int*   core = (const int*)  d_in[1];
    const int*   tgt  = (const int*)  d_in[2];
    const float* W    = (const float*)d_in[3];
    const float* ap   = (const float*)d_in[4];
    // d_in[5]/d_in[6] (lin_w, lin_b) only feed attention_viz, which is not returned.

    unsigned short* Wt = (unsigned short*)d_ws;         // 128*128 bf16 = 32 KB

    float* out_p = (float*)d_out;                       // (8,128,1024,32)
    float* att_p = out_p + (size_t)8 * 128 * 1024 * 32; // (8,1024,32,128)

    prep_wt<<<dim3(64), dim3(256), 0, stream>>>(W, Wt);
    fused_gat_mfma<<<dim3(1024), dim3(256), 0, stream>>>(x, core, tgt, Wt, ap, out_p, att_p);
}

// Round 5
// 109.566 us; speedup vs baseline: 1.1160x; 1.1160x over previous
//
#include <hip/hip_runtime.h>
#include <hip/hip_bf16.h>

// Fused GAT layer, bf16-MFMA, round 5 = R2 winner + register-pressure fixes ONLY.
// - per-n-row MFMA+epilogue (acc 16 regs, ev in place 16 regs; unroll 1 keeps halves apart)
// - all f32->bf16 via v_cvt_pk_bf16_f32 (staging + inline W gather), no prep kernel
// - __launch_bounds__(256,4): cap VGPR at 128 -> 16 waves/CU (est. true need ~105)
// Layout (m89): acc[h][gt]: m = nl*32+16h+(lane>>4)*4+r, g = 32wv+16gt+(lane&15)

#define NK 32768
#define NEG_SLOPE 0.2f

using f32x4 = __attribute__((ext_vector_type(4))) float;
using s16x8 = __attribute__((ext_vector_type(8))) short;

__global__ __launch_bounds__(256, 4) void fused_gat_mfma(
    const float* __restrict__ x,
    const int*   __restrict__ core_types,
    const int*   __restrict__ target_types,
    const float* __restrict__ W,
    const float* __restrict__ a_pair,
    float* __restrict__ out,
    float* __restrict__ att_out)
{
    __shared__ __align__(16) unsigned short xs[64 * 136];   // x^T tile bf16: [m][f], +8 pad

    const int t    = threadIdx.x;
    const int wv   = __builtin_amdgcn_readfirstlane(t >> 6);
    const int lane = t & 63;
    const int l15  = lane & 15;
    const int l4   = lane >> 4;
    const int b    = blockIdx.x >> 9;
    const int n0   = (blockIdx.x & 511) * 2;

    // ---- stage x^T tile as bf16 (transpose; packed cvt_pk + b32 LDS writes)
    {
        const float* xb = x + (size_t)b * 128 * NK + (size_t)n0 * 32;
        const int m   = t & 63;
        const int fp0 = t >> 6;
        unsigned int* xs32 = (unsigned int*)xs;
        #pragma unroll
        for (int r = 0; r < 16; ++r) {
            const int fp = fp0 + r * 4;                     // f-pair 0..63
            const float lo = xb[(size_t)(2 * fp)     * NK + m];
            const float hi = xb[(size_t)(2 * fp + 1) * NK + m];
            __hip_bfloat162 h2 = __float22bfloat162_rn(make_float2(lo, hi));
            xs32[m * 68 + fp] = *(const unsigned*)&h2;      // v_cvt_pk_bf16_f32
        }
    }

    // ---- B fragments inline from fp32 W (L2-hot), packed converts
    s16x8 bfrag[2][4];
    #pragma unroll
    for (int gt = 0; gt < 2; ++gt) {
        const float* wg = W + wv * 32 + gt * 16 + l15;      // column g
        #pragma unroll
        for (int fs = 0; fs < 4; ++fs) {
            #pragma unroll
            for (int i2 = 0; i2 < 4; ++i2) {
                const int f = fs * 32 + l4 * 8 + i2 * 2;
                __hip_bfloat162 h2 = __float22bfloat162_rn(
                    make_float2(wg[(size_t)f * 128], wg[(size_t)(f + 1) * 128]));
                ((unsigned*)&bfrag[gt][fs])[i2] = *(const unsigned*)&h2;
            }
        }
    }

    const int c01[2] = { core_types[b * 1024 + n0], core_types[b * 1024 + n0 + 1] };

    __syncthreads();

    // ---- per n-row: MFMA + epilogue (acc stays at 16 regs)
    #pragma unroll 1
    for (int nl = 0; nl < 2; ++nl) {
        const int n = n0 + nl;

        f32x4 acc[2][2];
        #pragma unroll
        for (int h = 0; h < 2; ++h)
            #pragma unroll
            for (int gt = 0; gt < 2; ++gt)
                acc[h][gt] = (f32x4){0.f, 0.f, 0.f, 0.f};

        #pragma unroll
        for (int fs = 0; fs < 4; ++fs) {
            s16x8 a0 = *(const s16x8*)&xs[(nl * 32 +      l15) * 136 + fs * 32 + l4 * 8];
            s16x8 a1 = *(const s16x8*)&xs[(nl * 32 + 16 + l15) * 136 + fs * 32 + l4 * 8];
            #pragma unroll
            for (int gt = 0; gt < 2; ++gt) {
                acc[0][gt] = __builtin_amdgcn_mfma_f32_16x16x32_bf16(a0, bfrag[gt][fs], acc[0][gt], 0, 0, 0);
                acc[1][gt] = __builtin_amdgcn_mfma_f32_16x16x32_bf16(a1, bfrag[gt][fs], acc[1][gt], 0, 0, 0);
            }
        }

        // e = leaky_relu(Wh * a) (in place -> att)
        const int cc = c01[nl];
        float ev[2][2][4];
        #pragma unroll
        for (int h = 0; h < 2; ++h) {
            const int kb = 16 * h + l4 * 4;
            const int4 tt4 = *(const int4*)&target_types[((size_t)(b * 1024 + n)) * 32 + kb];
            const int ttv[4] = {tt4.x, tt4.y, tt4.z, tt4.w};
            #pragma unroll
            for (int r = 0; r < 4; ++r) {
                const int tv = ttv[r];
                const int lo = min(cc, tv), hi = max(cc, tv);
                const int idx = lo * (17 - lo) / 2 + (hi - lo);
                const float* arow = a_pair + idx * 128 + wv * 32 + l15;
                #pragma unroll
                for (int gt = 0; gt < 2; ++gt) {
                    const float e = acc[h][gt][r] * arow[gt * 16];
                    ev[h][gt][r] = e > 0.f ? e : NEG_SLOPE * e;
                }
            }
        }

        // softmax over k (8 regs x 4-lane group: xor 16, 32)
        #pragma unroll
        for (int gt = 0; gt < 2; ++gt) {
            float mx = -1e30f;
            #pragma unroll
            for (int h = 0; h < 2; ++h)
                #pragma unroll
                for (int r = 0; r < 4; ++r) mx = fmaxf(mx, ev[h][gt][r]);
            mx = fmaxf(mx, __shfl_xor(mx, 16));
            mx = fmaxf(mx, __shfl_xor(mx, 32));
            float sm = 0.f;
            #pragma unroll
            for (int h = 0; h < 2; ++h)
                #pragma unroll
                for (int r = 0; r < 4; ++r) {
                    const float p = __expf(ev[h][gt][r] - mx);
                    ev[h][gt][r] = p;
                    sm += p;
                }
            sm += __shfl_xor(sm, 16);
            sm += __shfl_xor(sm, 32);
            const float inv = __fdividef(1.f, sm);
            #pragma unroll
            for (int h = 0; h < 2; ++h)
                #pragma unroll
                for (int r = 0; r < 4; ++r) ev[h][gt][r] *= inv;
        }

        // stores
        #pragma unroll
        for (int h = 0; h < 2; ++h) {
            const int kb = 16 * h + l4 * 4;
            #pragma unroll
            for (int gt = 0; gt < 2; ++gt) {
                const int g = wv * 32 + gt * 16 + l15;
                f32x4 ov;
                #pragma unroll
                for (int r = 0; r < 4; ++r) {
                    const float hh = ev[h][gt][r] * acc[h][gt][r];
                    ov[r] = hh > 0.f ? hh : __expf(hh) - 1.f;
                }
                *(f32x4*)&out[(size_t)b * 128 * NK + (size_t)g * NK + n * 32 + kb] = ov;
            }
            #pragma unroll
            for (int r = 0; r < 4; ++r) {
                const size_t abase = (((size_t)(b * 1024 + n)) * 32 + kb + r) * 128 + wv * 32 + l15;
                att_out[abase]      = ev[h][0][r];
                att_out[abase + 16] = ev[h][1][r];
            }
        }
    }
}

extern "C" void kernel_launch(void* const* d_in, const int* in_sizes, int n_in,
                              void* d_out, int out_size, void* d_ws, size_t ws_size,
                              hipStream_t stream) {
    const float* x    = (const float*)d_in[0];
    const int*   core = (const int*)  d_in[1];
    const int*   tgt  = (const int*)  d_in[2];
    const float* W    = (const float*)d_in[3];
    const float* ap   = (const float*)d_in[4];
    // d_in[5]/d_in[6] (lin_w, lin_b) only feed attention_viz, which is not returned.

    float* out_p = (float*)d_out;                       // (8,128,1024,32)
    float* att_p = out_p + (size_t)8 * 128 * 1024 * 32; // (8,1024,32,128)

    fused_gat_mfma<<<dim3(4096), dim3(256), 0, stream>>>(x, core, tgt, W, ap, out_p, att_p);
}

// Round 6
// 78.523 us; speedup vs baseline: 1.5572x; 1.3953x over previous
//
#include <hip/hip_runtime.h>
#include <hip/hip_bf16.h>

// Fused GAT layer, round 6: barrier-free per-wave design.
// Wave = (b, n, g-half). No LDS, no __syncthreads. A-frags gathered per-wave
// straight from x (the two g-half waves of one n sit in the same block -> L1
// line sharing). W-frags gathered inline (L2-hot). Outputs non-temporal.
// MFMA 16x16x32 bf16, m89 layout: A row=l15,k=l4*8+i ; C: g=l15-col, k-row=l4*4+r.
// Softmax over k = 8 regs (mt,r) x lanes l4 (shfl_xor 16,32), per gt.

#define NK 32768
#define NEG_SLOPE 0.2f

using f32x4 = __attribute__((ext_vector_type(4))) float;
using s16x8 = __attribute__((ext_vector_type(8))) short;

__global__ __launch_bounds__(256, 4) void fused_gat_wave(
    const float* __restrict__ x,
    const int*   __restrict__ core_types,
    const int*   __restrict__ target_types,
    const float* __restrict__ W,
    const float* __restrict__ a_pair,
    float* __restrict__ out,
    float* __restrict__ att_out)
{
    const int t    = threadIdx.x;
    const int lane = t & 63, l15 = lane & 15, l4 = lane >> 4;
    const int wv   = t >> 6;                  // 0..3
    const int nl   = wv >> 1, half = wv & 1;  // wave -> (n-local, g-half)
    const int b    = blockIdx.x >> 9;
    const int n    = (blockIdx.x & 511) * 2 + nl;

    const float* xb = x + (size_t)b * 128 * NK + n * 32;   // + f*NK + k
    const float* wb = W + half * 64 + l15;                 // + f*128 + gt*16

    // ---- MFMA fs-loop: acc[mt][gt], k-row = 16mt + l4*4 + r, g = half*64 + gt*16 + l15
    f32x4 acc[2][4];
    #pragma unroll
    for (int mt = 0; mt < 2; ++mt)
        #pragma unroll
        for (int gt = 0; gt < 4; ++gt) acc[mt][gt] = (f32x4){0.f, 0.f, 0.f, 0.f};

    #pragma unroll
    for (int fs = 0; fs < 4; ++fs) {
        const int f0 = fs * 32 + l4 * 8;

        s16x8 bfrag[4];
        #pragma unroll
        for (int gt = 0; gt < 4; ++gt)
            #pragma unroll
            for (int i2 = 0; i2 < 4; ++i2) {
                const int f = f0 + 2 * i2;
                __hip_bfloat162 h2 = __float22bfloat162_rn(make_float2(
                    wb[(size_t)f * 128 + gt * 16], wb[(size_t)(f + 1) * 128 + gt * 16]));
                ((unsigned*)&bfrag[gt])[i2] = *(const unsigned*)&h2;
            }

        s16x8 afrag[2];
        #pragma unroll
        for (int mt = 0; mt < 2; ++mt)
            #pragma unroll
            for (int i2 = 0; i2 < 4; ++i2) {
                const int f = f0 + 2 * i2;
                __hip_bfloat162 h2 = __float22bfloat162_rn(make_float2(
                    xb[(size_t)f * NK + 16 * mt + l15],
                    xb[(size_t)(f + 1) * NK + 16 * mt + l15]));
                ((unsigned*)&afrag[mt])[i2] = *(const unsigned*)&h2;
            }

        #pragma unroll
        for (int mt = 0; mt < 2; ++mt)
            #pragma unroll
            for (int gt = 0; gt < 4; ++gt)
                acc[mt][gt] = __builtin_amdgcn_mfma_f32_16x16x32_bf16(
                    afrag[mt], bfrag[gt], acc[mt][gt], 0, 0, 0);
    }

    // ---- e = leaky_relu(Wh * a)
    const int cc = core_types[b * 1024 + n];
    float ev[2][4][4];
    #pragma unroll
    for (int mt = 0; mt < 2; ++mt) {
        const int kb = 16 * mt + l4 * 4;
        const int4 tt4 = *(const int4*)&target_types[((size_t)(b * 1024 + n)) * 32 + kb];
        const int ttv[4] = {tt4.x, tt4.y, tt4.z, tt4.w};
        #pragma unroll
        for (int r = 0; r < 4; ++r) {
            const int tv = ttv[r];
            const int lo = min(cc, tv), hi = max(cc, tv);
            const int idx = lo * (17 - lo) / 2 + (hi - lo);
            const float* arow = a_pair + idx * 128 + half * 64 + l15;
            #pragma unroll
            for (int gt = 0; gt < 4; ++gt) {
                const float e = acc[mt][gt][r] * arow[gt * 16];
                ev[mt][gt][r] = e > 0.f ? e : NEG_SLOPE * e;
            }
        }
    }

    // ---- softmax over k (8 regs x 4-lane group: xor 16, 32), per gt
    #pragma unroll
    for (int gt = 0; gt < 4; ++gt) {
        float mx = -1e30f;
        #pragma unroll
        for (int mt = 0; mt < 2; ++mt)
            #pragma unroll
            for (int r = 0; r < 4; ++r) mx = fmaxf(mx, ev[mt][gt][r]);
        mx = fmaxf(mx, __shfl_xor(mx, 16));
        mx = fmaxf(mx, __shfl_xor(mx, 32));
        float sm = 0.f;
        #pragma unroll
        for (int mt = 0; mt < 2; ++mt)
            #pragma unroll
            for (int r = 0; r < 4; ++r) {
                const float p = __expf(ev[mt][gt][r] - mx);
                ev[mt][gt][r] = p;
                sm += p;
            }
        sm += __shfl_xor(sm, 16);
        sm += __shfl_xor(sm, 32);
        const float inv = __fdividef(1.f, sm);
        #pragma unroll
        for (int mt = 0; mt < 2; ++mt)
            #pragma unroll
            for (int r = 0; r < 4; ++r) ev[mt][gt][r] *= inv;
    }

    // ---- stores (non-temporal: write streams are never re-read)
    #pragma unroll
    for (int mt = 0; mt < 2; ++mt) {
        const int kb = 16 * mt + l4 * 4;
        #pragma unroll
        for (int gt = 0; gt < 4; ++gt) {
            const int g = half * 64 + gt * 16 + l15;
            f32x4 ov;
            #pragma unroll
            for (int r = 0; r < 4; ++r) {
                const float hh = ev[mt][gt][r] * acc[mt][gt][r];
                ov[r] = hh > 0.f ? hh : __expf(hh) - 1.f;
            }
            __builtin_nontemporal_store(
                ov, (f32x4*)&out[(size_t)b * 128 * NK + (size_t)g * NK + n * 32 + kb]);
        }
        #pragma unroll
        for (int r = 0; r < 4; ++r) {
            const size_t abase = (((size_t)(b * 1024 + n)) * 32 + kb + r) * 128 + half * 64 + l15;
            #pragma unroll
            for (int gt = 0; gt < 4; ++gt)
                __builtin_nontemporal_store(ev[mt][gt][r], &att_out[abase + gt * 16]);
        }
    }
}

extern "C" void kernel_launch(void* const* d_in, const int* in_sizes, int n_in,
                              void* d_out, int out_size, void* d_ws, size_t ws_size,
                              hipStream_t stream) {
    const float* x    = (const float*)d_in[0];
    const int*   core = (const int*)  d_in[1];
    const int*   tgt  = (const int*)  d_in[2];
    const float* W    = (const float*)d_in[3];
    const float* ap   = (const float*)d_in[4];
    // d_in[5]/d_in[6] (lin_w, lin_b) only feed attention_viz, which is not returned.

    float* out_p = (float*)d_out;                       // (8,128,1024,32)
    float* att_p = out_p + (size_t)8 * 128 * 1024 * 32; // (8,1024,32,128)

    fused_gat_wave<<<dim3(4096), dim3(256), 0, stream>>>(x, core, tgt, W, ap, out_p, att_p);
}

// Round 8
// 76.299 us; speedup vs baseline: 1.6026x; 1.0291x over previous
//
#include <hip/hip_runtime.h>
#include <hip/hip_bf16.h>

// Fused GAT layer, round 8: R6 barrier-free per-wave design + VMEM diet,
// SINGLE kernel (prep-kernel pattern diverged under graph replay in R7 and
// always cost ~6-8 us serial launch; W is gathered inline instead).
// Wave = (b, n, g-half); no LDS, no __syncthreads.
// INTERLEAVED g-mapping: g = half*64 + 4*l15 + gt. Consequences:
//   - W row f: lanes l15 x gt cover g contiguously -> one float4/f-row (32 loads total)
//   - a_pair: one float4 per (mt,r)      (8 loads)
//   - att: one f32x4 store per (mt,r)    (8 stores)
// VMEM/thread ~122 (was 266 in R6). Bytes unchanged; W/a_pair L1/L2-hot.
// MFMA 16x16x32 bf16, m89 layout: C col = l15 -> g-group, row = l4*4+r -> k.

#define NK 32768
#define NEG_SLOPE 0.2f

using f32x4 = __attribute__((ext_vector_type(4))) float;
using s16x8 = __attribute__((ext_vector_type(8))) short;

__global__ __launch_bounds__(256, 4) void fused_gat_wave(
    const float* __restrict__ x,
    const int*   __restrict__ core_types,
    const int*   __restrict__ target_types,
    const float* __restrict__ W,
    const float* __restrict__ a_pair,
    float* __restrict__ out,
    float* __restrict__ att_out)
{
    const int t    = threadIdx.x;
    const int lane = t & 63, l15 = lane & 15, l4 = lane >> 4;
    const int wv   = t >> 6;                  // 0..3
    const int nl   = wv >> 1, half = wv & 1;  // wave -> (n-local, g-half)
    const int b    = blockIdx.x >> 9;
    const int n    = (blockIdx.x & 511) * 2 + nl;

    const float* xb = x + (size_t)b * 128 * NK + n * 32;   // + f*NK + k
    const int    g0 = half * 64 + 4 * l15;                 // lane's base g; g = g0 + gt
    const float* wb = W + g0;                              // + f*128

    // ---- MFMA fs-loop: acc[mt][gt], k = 16mt + l4*4 + r, g = g0 + gt
    f32x4 acc[2][4];
    #pragma unroll
    for (int mt = 0; mt < 2; ++mt)
        #pragma unroll
        for (int gt = 0; gt < 4; ++gt) acc[mt][gt] = (f32x4){0.f, 0.f, 0.f, 0.f};

    #pragma unroll
    for (int fs = 0; fs < 4; ++fs) {
        const int f0 = fs * 32 + l4 * 8;

        // W: one float4 per f-row (covers gt=0..3), repack to bf16 fragments
        s16x8 bfrag[4];
        #pragma unroll
        for (int fp = 0; fp < 4; ++fp) {                   // f = f0 + 2fp (+1)
            const f32x4 we = *(const f32x4*)&wb[(size_t)(f0 + 2 * fp)     * 128];
            const f32x4 wo = *(const f32x4*)&wb[(size_t)(f0 + 2 * fp + 1) * 128];
            #pragma unroll
            for (int gt = 0; gt < 4; ++gt) {
                __hip_bfloat162 h2 = __float22bfloat162_rn(make_float2(we[gt], wo[gt]));
                ((unsigned*)&bfrag[gt])[fp] = *(const unsigned*)&h2;
            }
        }

        s16x8 afrag[2];
        #pragma unroll
        for (int mt = 0; mt < 2; ++mt)
            #pragma unroll
            for (int i2 = 0; i2 < 4; ++i2) {
                const int f = f0 + 2 * i2;
                __hip_bfloat162 h2 = __float22bfloat162_rn(make_float2(
                    xb[(size_t)f * NK + 16 * mt + l15],
                    xb[(size_t)(f + 1) * NK + 16 * mt + l15]));
                ((unsigned*)&afrag[mt])[i2] = *(const unsigned*)&h2;
            }

        #pragma unroll
        for (int mt = 0; mt < 2; ++mt)
            #pragma unroll
            for (int gt = 0; gt < 4; ++gt)
                acc[mt][gt] = __builtin_amdgcn_mfma_f32_16x16x32_bf16(
                    afrag[mt], bfrag[gt], acc[mt][gt], 0, 0, 0);
    }

    // ---- e = leaky_relu(Wh * a)   (a_pair: one float4 per (mt,r))
    const int cc = core_types[b * 1024 + n];
    float ev[2][4][4];
    #pragma unroll
    for (int mt = 0; mt < 2; ++mt) {
        const int kb = 16 * mt + l4 * 4;
        const int4 tt4 = *(const int4*)&target_types[((size_t)(b * 1024 + n)) * 32 + kb];
        const int ttv[4] = {tt4.x, tt4.y, tt4.z, tt4.w};
        #pragma unroll
        for (int r = 0; r < 4; ++r) {
            const int tv = ttv[r];
            const int lo = min(cc, tv), hi = max(cc, tv);
            const int idx = lo * (17 - lo) / 2 + (hi - lo);
            const f32x4 a4 = *(const f32x4*)&a_pair[idx * 128 + g0];
            #pragma unroll
            for (int gt = 0; gt < 4; ++gt) {
                const float e = acc[mt][gt][r] * a4[gt];
                ev[mt][gt][r] = e > 0.f ? e : NEG_SLOPE * e;
            }
        }
    }

    // ---- softmax over k (8 regs x 4-lane group: xor 16, 32), per gt
    #pragma unroll
    for (int gt = 0; gt < 4; ++gt) {
        float mx = -1e30f;
        #pragma unroll
        for (int mt = 0; mt < 2; ++mt)
            #pragma unroll
            for (int r = 0; r < 4; ++r) mx = fmaxf(mx, ev[mt][gt][r]);
        mx = fmaxf(mx, __shfl_xor(mx, 16));
        mx = fmaxf(mx, __shfl_xor(mx, 32));
        float sm = 0.f;
        #pragma unroll
        for (int mt = 0; mt < 2; ++mt)
            #pragma unroll
            for (int r = 0; r < 4; ++r) {
                const float p = __expf(ev[mt][gt][r] - mx);
                ev[mt][gt][r] = p;
                sm += p;
            }
        sm += __shfl_xor(sm, 16);
        sm += __shfl_xor(sm, 32);
        const float inv = __fdividef(1.f, sm);
        #pragma unroll
        for (int mt = 0; mt < 2; ++mt)
            #pragma unroll
            for (int r = 0; r < 4; ++r) ev[mt][gt][r] *= inv;
    }

    // ---- stores (non-temporal: write streams never re-read; protect x's L3 residency)
    #pragma unroll
    for (int mt = 0; mt < 2; ++mt) {
        const int kb = 16 * mt + l4 * 4;
        #pragma unroll
        for (int gt = 0; gt < 4; ++gt) {
            f32x4 ov;
            #pragma unroll
            for (int r = 0; r < 4; ++r) {
                const float hh = ev[mt][gt][r] * acc[mt][gt][r];
                ov[r] = hh > 0.f ? hh : __expf(hh) - 1.f;
            }
            __builtin_nontemporal_store(
                ov, (f32x4*)&out[(size_t)b * 128 * NK + (size_t)(g0 + gt) * NK + n * 32 + kb]);
        }
        #pragma unroll
        for (int r = 0; r < 4; ++r) {
            f32x4 av = {ev[mt][0][r], ev[mt][1][r], ev[mt][2][r], ev[mt][3][r]};
            __builtin_nontemporal_store(
                av, (f32x4*)&att_out[(((size_t)(b * 1024 + n)) * 32 + kb + r) * 128 + g0]);
        }
    }
}

extern "C" void kernel_launch(void* const* d_in, const int* in_sizes, int n_in,
                              void* d_out, int out_size, void* d_ws, size_t ws_size,
                              hipStream_t stream) {
    const float* x    = (const float*)d_in[0];
    const int*   core = (const int*)  d_in[1];
    const int*   tgt  = (const int*)  d_in[2];
    const float* W    = (const float*)d_in[3];
    const float* ap   = (const float*)d_in[4];
    // d_in[5]/d_in[6] (lin_w, lin_b) only feed attention_viz, which is not returned.

    float* out_p = (float*)d_out;                       // (8,128,1024,32)
    float* att_p = out_p + (size_t)8 * 128 * 1024 * 32; // (8,1024,32,128)

    fused_gat_wave<<<dim3(4096), dim3(256), 0, stream>>>(x, core, tgt, W, ap, out_p, att_p);
}